// Round 3
// baseline (1084.613 us; speedup 1.0000x reference)
//
#include <hip/hip_runtime.h>

// SkipLSTM: B=256, T=784, I=1, H=110, NCLS=10
// One block per batch element, 896 threads (14 waves), 880 active.
// 8-lane group per hidden unit: group u computes gate rows u, u+110,
// u+220, u+330 (i,f,g,o). Lane j of the group holds k-chunks
// {4j..4j+3, 32+4j.., 64+.., 96+..} of all 4 rows -> 16 float4 = 64 VGPRs.
// Gate reduce across the 8 lanes via DPP (xor1, xor2, half_mirror) -> the
// SAME lanes apply activations + c/h update in registers: no s_act LDS
// round-trip, no phase-2. h double-buffered in LDS; lane j reads h chunks
// j, j+8, j+16, j+24 -> bank-quads 4j all distinct -> conflict-free.
// du-reduction in wave 0 only, cached across skip steps (c unchanged => du
// unchanged). __launch_bounds__(896,4) -> 128-VGPR cap, keeps weights in
// true VGPRs (round-2's (NT,1) let the allocator AGPR-park them).

#define T784 784
#define H110 110
#define NT   896
#define NCLS 10

__device__ __forceinline__ float sigm(float x) { return 1.0f / (1.0f + __expf(-x)); }
__device__ __forceinline__ float ftanh(float x) {
    float e = __expf(2.0f * x);
    return 1.0f - 2.0f / (e + 1.0f);
}
template <int CTRL>
__device__ __forceinline__ float dppadd(float v) {
    // v + dpp_perm(v): compiler folds to v_add_f32_dpp (VALU pipe, no DS)
    return v + __int_as_float(
        __builtin_amdgcn_update_dpp(0, __float_as_int(v), CTRL, 0xF, 0xF, true));
}

__global__ __launch_bounds__(NT, 4)
void skiplstm_kernel(const float* __restrict__ x,
                     const float* __restrict__ W_ih,
                     const float* __restrict__ W_hh,
                     const float* __restrict__ b,
                     const float* __restrict__ W_p,
                     const float* __restrict__ b_p,
                     const float* __restrict__ h0,
                     const float* __restrict__ c0,
                     const float* __restrict__ W_fc,
                     const float* __restrict__ b_fc,
                     float* __restrict__ out)
{
    __shared__ __align__(16) float s_hbuf[256];  // double-buffered h (128 each, pad 0)
    __shared__ float s_p[128];                   // c*W_p partials (110 live, pad 0)
    __shared__ float s_x[T784];
    __shared__ float s_ub[1];

    const int tid  = threadIdx.x;
    const int bb   = blockIdx.x;
    const int unit = tid >> 3;                   // 0..111 (110,111 inactive)
    const int j    = tid & 7;
    const bool act = (unit < H110);

    // ---- weight slices: w[g][i] = W_hh[unit+110g, 4(j+8i) .. +3] ----
    float4 w[4][4];
    float  bv[4], wv[4];
    #pragma unroll
    for (int g = 0; g < 4; ++g) {
        const int row = unit + H110 * g;
        bv[g] = act ? b[row]    : 0.0f;
        wv[g] = act ? W_ih[row] : 0.0f;
        const float* rp = W_hh + row * H110;
        #pragma unroll
        for (int i = 0; i < 4; ++i) {
            const int k0 = 4 * (j + 8 * i);
            float4 t = make_float4(0.f, 0.f, 0.f, 0.f);
            if (act) {
                if (k0 + 0 < H110) t.x = rp[k0 + 0];
                if (k0 + 1 < H110) t.y = rp[k0 + 1];
                if (k0 + 2 < H110) t.z = rp[k0 + 2];
                if (k0 + 3 < H110) t.w = rp[k0 + 3];
            }
            w[g][i] = t;
        }
    }
    float creg = act ? c0[unit] : 0.0f;
    float hreg = act ? h0[unit] : 0.0f;
    const float wp = act ? W_p[unit] : 0.0f;
    const float bp = b_p[0];

    for (int i = tid; i < 256;  i += NT) s_hbuf[i] = 0.0f;
    for (int i = tid; i < 128;  i += NT) s_p[i]    = 0.0f;
    for (int i = tid; i < T784; i += NT) s_x[i]    = x[bb * T784 + i];
    if (tid < H110) s_hbuf[tid] = h0[tid];       // same thread as the zero -> ordered
    if (tid == 0)   s_ub[0] = 1.0f;              // u0 = 1
    __syncthreads();

    float u_loc = 1.0f;                          // wave-0 state
    float du_c  = 0.0f;                          // cached du (valid after t=0)
    int   cnt   = 0;

    for (int t = 0; t < T784; ++t) {
        const float* hb = s_hbuf + ((t & 1) << 7);
        float*       hn = s_hbuf + (((t + 1) & 1) << 7);

        const float ubv = s_ub[0];
        const float xt  = s_x[t];
        const float4* h4 = (const float4*)hb;
        const float4 hA = h4[j];                 // bank-quads 4j: conflict-free
        const float4 hB = h4[j + 8];
        const float4 hC = h4[j + 16];
        const float4 hD = h4[j + 24];

        float a[4];
        #pragma unroll
        for (int g = 0; g < 4; ++g) {
            float s = fmaf(xt, wv[g], bv[g]);
            s = fmaf(hA.x, w[g][0].x, s); s = fmaf(hA.y, w[g][0].y, s);
            s = fmaf(hA.z, w[g][0].z, s); s = fmaf(hA.w, w[g][0].w, s);
            s = fmaf(hB.x, w[g][1].x, s); s = fmaf(hB.y, w[g][1].y, s);
            s = fmaf(hB.z, w[g][1].z, s); s = fmaf(hB.w, w[g][1].w, s);
            s = fmaf(hC.x, w[g][2].x, s); s = fmaf(hC.y, w[g][2].y, s);
            s = fmaf(hC.z, w[g][2].z, s); s = fmaf(hC.w, w[g][2].w, s);
            s = fmaf(hD.x, w[g][3].x, s); s = fmaf(hD.y, w[g][3].y, s);
            s = fmaf(hD.z, w[g][3].z, s); s = fmaf(hD.w, w[g][3].w, s);
            a[g] = s;
        }
        // 8-lane group reduce: xor1, xor2 (quad_perm), cross-quad (half_mirror)
        #pragma unroll
        for (int g = 0; g < 4; ++g) {
            a[g] = dppadd<0xB1>(a[g]);
            a[g] = dppadd<0x4E>(a[g]);
            a[g] = dppadd<0x141>(a[g]);
        }
        const float gi = sigm(a[0]);
        const float gf = sigm(a[1]);
        const float gg = ftanh(a[2]);
        const float go = sigm(a[3]);
        const float c_new = fmaf(gf, creg, gi * gg);
        const float h_new = go * ftanh(c_new);
        const bool  up = ubv > 0.5f;             // ub is exactly 0/1
        creg = up ? c_new : creg;
        hreg = up ? h_new : hreg;
        if (act && j == 0) {
            hn[unit]  = hreg;                    // pads [110..128) never touched
            s_p[unit] = creg * wp;
        }
        __syncthreads();                         // s_p, hn complete

        if (tid < 64) {                          // wave 0: du / u / ub
            if (up) {                            // c changed -> recompute du
                float v = s_p[tid] + s_p[tid + 64];
                #pragma unroll
                for (int off = 32; off; off >>= 1) v += __shfl_xor(v, off, 64);
                du_c  = sigm(v + bp);
                u_loc = du_c;
            } else {                             // c unchanged -> du cached
                u_loc = u_loc + fminf(du_c, 1.0f - u_loc);
            }
            cnt += up ? 1 : 0;
            if (tid == 0) s_ub[0] = rintf(u_loc); // round-half-even == jnp.round
        }
        __syncthreads();                         // s_ub visible for t+1
    }

    // epilogue: final h is in buffer 0 (t=783 wrote buf (784&1)=0)
    if (tid < NCLS) {
        float acc = b_fc[tid];
        for (int k = 0; k < H110; ++k)
            acc = fmaf(s_hbuf[k], W_fc[tid * H110 + k], acc);
        out[bb * NCLS + tid] = acc;
    }
    if (tid == 0)
        atomicAdd(out + 256 * NCLS, (float)cnt); // total_u at flat index 2560
}

__global__ void zero_tail_kernel(float* out) {
    if (threadIdx.x == 0) out[256 * NCLS] = 0.0f;   // d_out is poisoned 0xAA
}

extern "C" void kernel_launch(void* const* d_in, const int* in_sizes, int n_in,
                              void* d_out, int out_size, void* d_ws, size_t ws_size,
                              hipStream_t stream) {
    const float* x    = (const float*)d_in[0];
    const float* W_ih = (const float*)d_in[1];
    const float* W_hh = (const float*)d_in[2];
    const float* b    = (const float*)d_in[3];
    const float* W_p  = (const float*)d_in[4];
    const float* b_p  = (const float*)d_in[5];
    const float* h0   = (const float*)d_in[6];
    const float* c0   = (const float*)d_in[7];
    const float* W_fc = (const float*)d_in[8];
    const float* b_fc = (const float*)d_in[9];
    float* out = (float*)d_out;

    zero_tail_kernel<<<1, 64, 0, stream>>>(out);
    skiplstm_kernel<<<256, NT, 0, stream>>>(x, W_ih, W_hh, b, W_p, b_p,
                                            h0, c0, W_fc, b_fc, out);
}

// Round 4
// 984.236 us; speedup vs baseline: 1.1020x; 1.1020x over previous
//
#include <hip/hip_runtime.h>

// SkipLSTM: B=256, T=784, I=1, H=110, NCLS=10
// One block per batch element, 896 threads (14 waves), 880 active.
// 8-lane group per unit u computes gate rows u, u+110, u+220, u+330.
// Lane j holds k-chunks {4j, 32+4j, 64+4j, 96+4j} (4 floats each) of all
// 4 rows = 64 weight floats. ONE barrier per step: h and p double-buffered;
// u/du replicated per-wave (bitwise-identical reduce) so no ub broadcast.
// R3 lesson: transcendentals cost 8cyc/wave-instr and were replicated 5x on
// all 14 waves (+1200 cyc/step). Here: gate activation is ONE exp+rcp path
// per wave (lane j activates gate j&3 via tanh(x)=2*sigm(2x)-1 unification),
// redistributed with 4 quad_perm broadcasts.

#define T784 784
#define H110 110
#define NT   896
#define NCLS 10
#define LOG2E 1.44269504088896340736f

__device__ __forceinline__ float frcp(float x)  { return __builtin_amdgcn_rcpf(x); }
__device__ __forceinline__ float fexp2(float x) { return __builtin_amdgcn_exp2f(x); }

template <int CTRL>
__device__ __forceinline__ float dppmov(float v) {
    // old = v: lanes with invalid source keep v (only matters for bcast ctrls)
    return __int_as_float(__builtin_amdgcn_update_dpp(
        __float_as_int(v), __float_as_int(v), CTRL, 0xF, 0xF, false));
}
template <int CTRL>
__device__ __forceinline__ float dppadd(float v) { return v + dppmov<CTRL>(v); }

__global__ __launch_bounds__(NT, 2)
void skiplstm_kernel(const float* __restrict__ x,
                     const float* __restrict__ W_ih,
                     const float* __restrict__ W_hh,
                     const float* __restrict__ b,
                     const float* __restrict__ W_p,
                     const float* __restrict__ b_p,
                     const float* __restrict__ h0,
                     const float* __restrict__ c0,
                     const float* __restrict__ W_fc,
                     const float* __restrict__ b_fc,
                     float* __restrict__ out)
{
    __shared__ __align__(16) float s_hbuf[256];  // double-buffered h (128 each)
    __shared__ float s_pbuf[256];                // double-buffered c*W_p partials
    __shared__ float s_x[T784];

    const int tid  = threadIdx.x;
    const int bb   = blockIdx.x;
    const int unit = tid >> 3;                   // 0..111 (110,111 inactive)
    const int j    = tid & 7;
    const bool act = (unit < H110);

    // ---- weight slices: w[g][i] = W_hh[unit+110g, 4(j+8i) .. +3] ----
    float4 w[4][4];
    float  bv[4], wv[4];
    #pragma unroll
    for (int g = 0; g < 4; ++g) {
        const int row = unit + H110 * g;
        bv[g] = act ? b[row]    : 0.0f;
        wv[g] = act ? W_ih[row] : 0.0f;
        const float* rp = W_hh + row * H110;
        #pragma unroll
        for (int i = 0; i < 4; ++i) {
            const int k0 = 4 * (j + 8 * i);
            float4 t = make_float4(0.f, 0.f, 0.f, 0.f);
            if (act) {
                if (k0 + 0 < H110) t.x = rp[k0 + 0];
                if (k0 + 1 < H110) t.y = rp[k0 + 1];
                if (k0 + 2 < H110) t.z = rp[k0 + 2];
                if (k0 + 3 < H110) t.w = rp[k0 + 3];
            }
            w[g][i] = t;
        }
    }
    float creg = act ? c0[unit] : 0.0f;
    float hreg = act ? h0[unit] : 0.0f;
    const float wp = act ? W_p[unit] : 0.0f;
    const float bp = b_p[0];

    // per-lane activation constants: lane j activates gate (j&3); gate 2 is tanh
    const int  jg   = j & 3;
    const bool isg  = (jg == 2);
    const float negk = isg ? (-2.0f * LOG2E) : (-LOG2E);  // exp2 scale
    const float mulc = isg ? 2.0f : 1.0f;                 // tanh = 2*sigm(2x)-1
    const float addc = isg ? -1.0f : 0.0f;

    for (int i = tid; i < 256;  i += NT) { s_hbuf[i] = 0.0f; s_pbuf[i] = 0.0f; }
    for (int i = tid; i < T784; i += NT) s_x[i] = x[bb * T784 + i];
    __syncthreads();
    if (tid < H110) s_hbuf[tid] = h0[tid];
    __syncthreads();

    float u_loc = 1.0f;                          // replicated per-wave (identical)
    float du_c  = 0.0f;                          // cached du (c unchanged => du same)
    int   cnt   = 0;

    for (int t = 0; t < T784; ++t) {
        const float* hb = s_hbuf + ((t & 1) << 7);
        float*       hn = s_hbuf + (((t + 1) & 1) << 7);
        float*       pn = s_pbuf + (((t + 1) & 1) << 7);

        const float ub = rintf(u_loc);           // round-half-even == jnp.round
        const bool  up = ub > 0.5f;              // wave-uniform
        const float xt = s_x[t];

        const float4* h4 = (const float4*)hb;
        const float4 hA = h4[j];                 // bank-quads 4j: conflict-free
        const float4 hB = h4[j + 8];
        const float4 hC = h4[j + 16];
        const float4 hD = h4[j + 24];

        float a0, a1, a2, a3;
        {
            float s;
            s = fmaf(xt, wv[0], bv[0]);
            s = fmaf(hA.x, w[0][0].x, s); s = fmaf(hA.y, w[0][0].y, s);
            s = fmaf(hA.z, w[0][0].z, s); s = fmaf(hA.w, w[0][0].w, s);
            s = fmaf(hB.x, w[0][1].x, s); s = fmaf(hB.y, w[0][1].y, s);
            s = fmaf(hB.z, w[0][1].z, s); s = fmaf(hB.w, w[0][1].w, s);
            s = fmaf(hC.x, w[0][2].x, s); s = fmaf(hC.y, w[0][2].y, s);
            s = fmaf(hC.z, w[0][2].z, s); s = fmaf(hC.w, w[0][2].w, s);
            s = fmaf(hD.x, w[0][3].x, s); s = fmaf(hD.y, w[0][3].y, s);
            s = fmaf(hD.z, w[0][3].z, s); s = fmaf(hD.w, w[0][3].w, s);
            a0 = s;
            s = fmaf(xt, wv[1], bv[1]);
            s = fmaf(hA.x, w[1][0].x, s); s = fmaf(hA.y, w[1][0].y, s);
            s = fmaf(hA.z, w[1][0].z, s); s = fmaf(hA.w, w[1][0].w, s);
            s = fmaf(hB.x, w[1][1].x, s); s = fmaf(hB.y, w[1][1].y, s);
            s = fmaf(hB.z, w[1][1].z, s); s = fmaf(hB.w, w[1][1].w, s);
            s = fmaf(hC.x, w[1][2].x, s); s = fmaf(hC.y, w[1][2].y, s);
            s = fmaf(hC.z, w[1][2].z, s); s = fmaf(hC.w, w[1][2].w, s);
            s = fmaf(hD.x, w[1][3].x, s); s = fmaf(hD.y, w[1][3].y, s);
            s = fmaf(hD.z, w[1][3].z, s); s = fmaf(hD.w, w[1][3].w, s);
            a1 = s;
            s = fmaf(xt, wv[2], bv[2]);
            s = fmaf(hA.x, w[2][0].x, s); s = fmaf(hA.y, w[2][0].y, s);
            s = fmaf(hA.z, w[2][0].z, s); s = fmaf(hA.w, w[2][0].w, s);
            s = fmaf(hB.x, w[2][1].x, s); s = fmaf(hB.y, w[2][1].y, s);
            s = fmaf(hB.z, w[2][1].z, s); s = fmaf(hB.w, w[2][1].w, s);
            s = fmaf(hC.x, w[2][2].x, s); s = fmaf(hC.y, w[2][2].y, s);
            s = fmaf(hC.z, w[2][2].z, s); s = fmaf(hC.w, w[2][2].w, s);
            s = fmaf(hD.x, w[2][3].x, s); s = fmaf(hD.y, w[2][3].y, s);
            s = fmaf(hD.z, w[2][3].z, s); s = fmaf(hD.w, w[2][3].w, s);
            a2 = s;
            s = fmaf(xt, wv[3], bv[3]);
            s = fmaf(hA.x, w[3][0].x, s); s = fmaf(hA.y, w[3][0].y, s);
            s = fmaf(hA.z, w[3][0].z, s); s = fmaf(hA.w, w[3][0].w, s);
            s = fmaf(hB.x, w[3][1].x, s); s = fmaf(hB.y, w[3][1].y, s);
            s = fmaf(hB.z, w[3][1].z, s); s = fmaf(hB.w, w[3][1].w, s);
            s = fmaf(hC.x, w[3][2].x, s); s = fmaf(hC.y, w[3][2].y, s);
            s = fmaf(hC.z, w[3][2].z, s); s = fmaf(hC.w, w[3][2].w, s);
            s = fmaf(hD.x, w[3][3].x, s); s = fmaf(hD.y, w[3][3].y, s);
            s = fmaf(hD.z, w[3][3].z, s); s = fmaf(hD.w, w[3][3].w, s);
            a3 = s;
        }
        // 8-lane reduce per gate: xor1, xor2 (quad_perm), half_mirror
        a0 = dppadd<0xB1>(a0); a1 = dppadd<0xB1>(a1);
        a2 = dppadd<0xB1>(a2); a3 = dppadd<0xB1>(a3);
        a0 = dppadd<0x4E>(a0); a1 = dppadd<0x4E>(a1);
        a2 = dppadd<0x4E>(a2); a3 = dppadd<0x4E>(a3);
        a0 = dppadd<0x141>(a0); a1 = dppadd<0x141>(a1);
        a2 = dppadd<0x141>(a2); a3 = dppadd<0x141>(a3);

        // lane j activates gate j&3 only: ONE exp + ONE rcp path per wave
        const float t01  = (j & 1) ? a1 : a0;
        const float t23  = (j & 1) ? a3 : a2;
        const float asel = (j & 2) ? t23 : t01;
        const float av   = fmaf(mulc, frcp(1.0f + fexp2(asel * negk)), addc);
        // redistribute: quad_perm broadcasts of lanes 0..3 within each quad
        const float gi = dppmov<0x00>(av);
        const float gf = dppmov<0x55>(av);
        const float gg = dppmov<0xAA>(av);
        const float go = dppmov<0xFF>(av);

        const float c_new = fmaf(gf, creg, gi * gg);
        const float th    = fmaf(2.0f, frcp(1.0f + fexp2(c_new * (-2.0f * LOG2E))), -1.0f);
        const float h_new = go * th;
        creg = up ? c_new : creg;                // ub is exactly 0/1
        hreg = up ? h_new : hreg;
        if (act && j == 0) {
            hn[unit] = hreg;                     // 8 lanes/wave, stride 32B: free
            pn[unit] = creg * wp;
        }
        __syncthreads();                         // the ONLY barrier per step

        // per-wave du (identical across waves). Skip steps reuse cached du.
        if (up) {
            const int lane = tid & 63;
            float v = pn[lane] + pn[lane + 64];
            v = dppadd<0xB1>(v);                 // xor1
            v = dppadd<0x4E>(v);                 // xor2
            v = dppadd<0x141>(v);                // half_mirror (xor across quads)
            v = dppadd<0x140>(v);                // row_mirror (xor across octets)
            v = dppadd<0x142>(v);                // bcast15: odd rows += even-row sum
            v = dppadd<0x143>(v);                // bcast31: upper half += lower sum
            const float tot = __int_as_float(
                __builtin_amdgcn_readlane(__float_as_int(v), 63));
            du_c  = frcp(1.0f + fexp2(-(tot + bp) * LOG2E));  // sigm
            u_loc = du_c;
            cnt  += 1;
        } else {
            u_loc = u_loc + fminf(du_c, 1.0f - u_loc);
        }
    }

    // epilogue: final h is in buffer 0 (t=783 wrote buf (784&1)=0)
    if (tid < NCLS) {
        float acc = b_fc[tid];
        for (int k = 0; k < H110; ++k)
            acc = fmaf(s_hbuf[k], W_fc[tid * H110 + k], acc);
        out[bb * NCLS + tid] = acc;
    }
    if (tid == 0)
        atomicAdd(out + 256 * NCLS, (float)cnt); // total_u at flat index 2560
}

__global__ void zero_tail_kernel(float* out) {
    if (threadIdx.x == 0) out[256 * NCLS] = 0.0f;   // d_out is poisoned 0xAA
}

extern "C" void kernel_launch(void* const* d_in, const int* in_sizes, int n_in,
                              void* d_out, int out_size, void* d_ws, size_t ws_size,
                              hipStream_t stream) {
    const float* x    = (const float*)d_in[0];
    const float* W_ih = (const float*)d_in[1];
    const float* W_hh = (const float*)d_in[2];
    const float* b    = (const float*)d_in[3];
    const float* W_p  = (const float*)d_in[4];
    const float* b_p  = (const float*)d_in[5];
    const float* h0   = (const float*)d_in[6];
    const float* c0   = (const float*)d_in[7];
    const float* W_fc = (const float*)d_in[8];
    const float* b_fc = (const float*)d_in[9];
    float* out = (float*)d_out;

    zero_tail_kernel<<<1, 64, 0, stream>>>(out);
    skiplstm_kernel<<<256, NT, 0, stream>>>(x, W_ih, W_hh, b, W_p, b_p,
                                            h0, c0, W_fc, b_fc, out);
}

// Round 5
// 933.217 us; speedup vs baseline: 1.1622x; 1.0547x over previous
//
#include <hip/hip_runtime.h>

// SkipLSTM: B=256, T=784, I=1, H=110, NCLS=10
// One block per batch element, 896 threads (14 waves), 880 active.
// 8-lane group per unit u computes gate rows u, u+110, u+220, u+330.
// Lane j holds k-chunks {4j, 32+4j, 64+4j, 96+4j} of all 4 rows, packed as
// float2 -> 32 v_pk_fma_f32 per step (was 64 scalar v_fma: R4 was VALU-
// issue-bound at 83% busy, so packed fp32 halves the dominant term).
// Inline-asm pk_fma with "v" constraints also pins weights in arch VGPRs
// (no AGPR parking). One barrier/step; h and p double-buffered; u/du
// replicated per-wave (bitwise-identical reduce). t-loop unrolled x2 so
// buffer pointers are static. Gate activation: ONE exp+rcp path per wave
// (lane j activates gate j&3 via tanh(x)=2*sigm(2x)-1), redistributed with
// 4 quad_perm broadcasts.

#define T784 784
#define H110 110
#define NT   896
#define NCLS 10
#define LOG2E 1.44269504088896340736f

typedef float v2f __attribute__((ext_vector_type(2)));
typedef float v4f __attribute__((ext_vector_type(4)));

__device__ __forceinline__ float frcp(float x)  { return __builtin_amdgcn_rcpf(x); }
__device__ __forceinline__ float fexp2(float x) { return __builtin_amdgcn_exp2f(x); }

__device__ __forceinline__ v2f pk_fma(v2f a, v2f b, v2f c) {
    v2f d;
    asm("v_pk_fma_f32 %0, %1, %2, %3" : "=v"(d) : "v"(a), "v"(b), "v"(c));
    return d;
}

template <int CTRL>
__device__ __forceinline__ float dppmov(float v) {
    // old = v: lanes with invalid source keep v (matters for bcast ctrls)
    return __int_as_float(__builtin_amdgcn_update_dpp(
        __float_as_int(v), __float_as_int(v), CTRL, 0xF, 0xF, false));
}
template <int CTRL>
__device__ __forceinline__ float dppadd(float v) { return v + dppmov<CTRL>(v); }

__global__ __launch_bounds__(NT, 3)
void skiplstm_kernel(const float* __restrict__ x,
                     const float* __restrict__ W_ih,
                     const float* __restrict__ W_hh,
                     const float* __restrict__ b,
                     const float* __restrict__ W_p,
                     const float* __restrict__ b_p,
                     const float* __restrict__ h0,
                     const float* __restrict__ c0,
                     const float* __restrict__ W_fc,
                     const float* __restrict__ b_fc,
                     float* __restrict__ out)
{
    __shared__ __align__(16) float s_hbuf[256];  // double-buffered h (128 each)
    __shared__ float s_pbuf[256];                // double-buffered c*W_p partials
    __shared__ float s_x[T784];

    const int tid  = threadIdx.x;
    const int bb   = blockIdx.x;
    const int unit = tid >> 3;                   // 0..111 (110,111 inactive)
    const int j    = tid & 7;
    const bool act = (unit < H110);

    // ---- weight slices, packed float2: w2[g][2i+{0,1}] = row[4(j+8i)+{01,23}] ----
    v2f  w2[4][8];
    float bv[4], wv[4];
    #pragma unroll
    for (int g = 0; g < 4; ++g) {
        const int row = unit + H110 * g;
        bv[g] = act ? b[row]    : 0.0f;
        wv[g] = act ? W_ih[row] : 0.0f;
        const float* rp = W_hh + row * H110;
        #pragma unroll
        for (int i = 0; i < 4; ++i) {
            const int k0 = 4 * (j + 8 * i);
            float f0 = 0.f, f1 = 0.f, f2 = 0.f, f3 = 0.f;
            if (act) {
                if (k0 + 0 < H110) f0 = rp[k0 + 0];
                if (k0 + 1 < H110) f1 = rp[k0 + 1];
                if (k0 + 2 < H110) f2 = rp[k0 + 2];
                if (k0 + 3 < H110) f3 = rp[k0 + 3];
            }
            w2[g][2 * i].x     = f0; w2[g][2 * i].y     = f1;
            w2[g][2 * i + 1].x = f2; w2[g][2 * i + 1].y = f3;
        }
    }
    float creg = act ? c0[unit] : 0.0f;
    float hreg = act ? h0[unit] : 0.0f;
    const float wp = act ? W_p[unit] : 0.0f;
    const float bp = b_p[0];

    // per-lane activation constants: lane j activates gate (j&3); gate 2 is tanh
    const bool  isg  = ((j & 3) == 2);
    const float negk = isg ? (-2.0f * LOG2E) : (-LOG2E);
    const float mulc = isg ? 2.0f : 1.0f;                 // tanh = 2*sigm(2x)-1
    const float addc = isg ? -1.0f : 0.0f;

    for (int i = tid; i < 256;  i += NT) { s_hbuf[i] = 0.0f; s_pbuf[i] = 0.0f; }
    for (int i = tid; i < T784; i += NT) s_x[i] = x[bb * T784 + i];
    __syncthreads();
    if (tid < H110) s_hbuf[tid] = h0[tid];
    __syncthreads();

    float u_loc = 1.0f;                          // replicated per-wave (identical)
    float du_c  = 0.0f;                          // cached du (c unchanged => du same)
    int   cnt   = 0;

    auto step = [&](const float* hb, float* hn, float* pn, int t) {
        const float ub = rintf(u_loc);           // round-half-even == jnp.round
        const bool  up = ub > 0.5f;              // wave-uniform
        const float xt = s_x[t];

        const v4f* h4 = (const v4f*)hb;
        const v4f hA = h4[j];                    // bank-quads 4j: conflict-free
        const v4f hB = h4[j + 8];
        const v4f hC = h4[j + 16];
        const v4f hD = h4[j + 24];
        v2f hv[8];
        hv[0] = __builtin_shufflevector(hA, hA, 0, 1);
        hv[1] = __builtin_shufflevector(hA, hA, 2, 3);
        hv[2] = __builtin_shufflevector(hB, hB, 0, 1);
        hv[3] = __builtin_shufflevector(hB, hB, 2, 3);
        hv[4] = __builtin_shufflevector(hC, hC, 0, 1);
        hv[5] = __builtin_shufflevector(hC, hC, 2, 3);
        hv[6] = __builtin_shufflevector(hD, hD, 0, 1);
        hv[7] = __builtin_shufflevector(hD, hD, 2, 3);

        v2f acc0 = {0.f, 0.f}, acc1 = {0.f, 0.f};
        v2f acc2 = {0.f, 0.f}, acc3 = {0.f, 0.f};
        #pragma unroll
        for (int p = 0; p < 8; ++p) {
            acc0 = pk_fma(hv[p], w2[0][p], acc0);
            acc1 = pk_fma(hv[p], w2[1][p], acc1);
            acc2 = pk_fma(hv[p], w2[2][p], acc2);
            acc3 = pk_fma(hv[p], w2[3][p], acc3);
        }
        float a0 = (acc0.x + acc0.y) + fmaf(xt, wv[0], bv[0]);
        float a1 = (acc1.x + acc1.y) + fmaf(xt, wv[1], bv[1]);
        float a2 = (acc2.x + acc2.y) + fmaf(xt, wv[2], bv[2]);
        float a3 = (acc3.x + acc3.y) + fmaf(xt, wv[3], bv[3]);

        // 8-lane all-reduce per gate: xor1, xor2 (quad_perm), half_mirror
        a0 = dppadd<0xB1>(a0);  a1 = dppadd<0xB1>(a1);
        a2 = dppadd<0xB1>(a2);  a3 = dppadd<0xB1>(a3);
        a0 = dppadd<0x4E>(a0);  a1 = dppadd<0x4E>(a1);
        a2 = dppadd<0x4E>(a2);  a3 = dppadd<0x4E>(a3);
        a0 = dppadd<0x141>(a0); a1 = dppadd<0x141>(a1);
        a2 = dppadd<0x141>(a2); a3 = dppadd<0x141>(a3);

        // lane j activates gate j&3 only: ONE exp + ONE rcp path per wave
        const float t01  = (j & 1) ? a1 : a0;
        const float t23  = (j & 1) ? a3 : a2;
        const float asel = (j & 2) ? t23 : t01;
        const float av   = fmaf(mulc, frcp(1.0f + fexp2(asel * negk)), addc);
        const float gi = dppmov<0x00>(av);
        const float gf = dppmov<0x55>(av);
        const float gg = dppmov<0xAA>(av);
        const float go = dppmov<0xFF>(av);

        const float c_new = fmaf(gf, creg, gi * gg);
        const float th    = fmaf(2.0f, frcp(1.0f + fexp2(c_new * (-2.0f * LOG2E))), -1.0f);
        const float h_new = go * th;
        creg = up ? c_new : creg;                // ub is exactly 0/1
        hreg = up ? h_new : hreg;
        if (act && j == 0) {
            hn[unit] = hreg;
            pn[unit] = creg * wp;
        }
        __syncthreads();                         // the ONLY barrier per step

        // per-wave du (identical across waves). Skip steps reuse cached du.
        if (up) {
            const int lane = tid & 63;
            float v = pn[lane] + pn[lane + 64];
            v = dppadd<0xB1>(v);                 // xor1
            v = dppadd<0x4E>(v);                 // xor2
            v = dppadd<0x141>(v);                // half_mirror
            v = dppadd<0x140>(v);                // row_mirror
            v = dppadd<0x142>(v);                // bcast15
            v = dppadd<0x143>(v);                // bcast31
            const float tot = __int_as_float(
                __builtin_amdgcn_readlane(__float_as_int(v), 63));
            du_c  = frcp(1.0f + fexp2(-(tot + bp) * LOG2E));  // sigm
            u_loc = du_c;
            cnt  += 1;
        } else {
            u_loc = u_loc + fminf(du_c, 1.0f - u_loc);
        }
    };

    for (int t = 0; t < T784; t += 2) {
        step(s_hbuf,       s_hbuf + 128, s_pbuf,       t);      // buf0 -> buf1
        step(s_hbuf + 128, s_hbuf,       s_pbuf + 128, t + 1);  // buf1 -> buf0
    }

    // epilogue: final h is in buffer 0 (t=783 wrote buf 0)
    if (tid < NCLS) {
        float acc = b_fc[tid];
        for (int k = 0; k < H110; ++k)
            acc = fmaf(s_hbuf[k], W_fc[tid * H110 + k], acc);
        out[bb * NCLS + tid] = acc;
    }
    if (tid == 0)
        atomicAdd(out + 256 * NCLS, (float)cnt); // total_u at flat index 2560
}

__global__ void zero_tail_kernel(float* out) {
    if (threadIdx.x == 0) out[256 * NCLS] = 0.0f;   // d_out is poisoned 0xAA
}

extern "C" void kernel_launch(void* const* d_in, const int* in_sizes, int n_in,
                              void* d_out, int out_size, void* d_ws, size_t ws_size,
                              hipStream_t stream) {
    const float* x    = (const float*)d_in[0];
    const float* W_ih = (const float*)d_in[1];
    const float* W_hh = (const float*)d_in[2];
    const float* b    = (const float*)d_in[3];
    const float* W_p  = (const float*)d_in[4];
    const float* b_p  = (const float*)d_in[5];
    const float* h0   = (const float*)d_in[6];
    const float* c0   = (const float*)d_in[7];
    const float* W_fc = (const float*)d_in[8];
    const float* b_fc = (const float*)d_in[9];
    float* out = (float*)d_out;

    zero_tail_kernel<<<1, 64, 0, stream>>>(out);
    skiplstm_kernel<<<256, NT, 0, stream>>>(x, W_ih, W_hh, b, W_p, b_p,
                                            h0, c0, W_fc, b_fc, out);
}

// Round 6
// 637.215 us; speedup vs baseline: 1.7021x; 1.4645x over previous
//
#include <hip/hip_runtime.h>

// SkipLSTM: B=256, T=784, I=1, H=110, NCLS=10
// One block per batch element, 448 threads = 7 WAVES (2 waves/SIMD ->
// 256-VGPR cap). R2-R5 lesson: a 14-wave block caps at 128 regs/lane and
// the allocator AGPR-parks the weights, paying v_accvgpr_read per use.
// 4-lane group per unit u; lane j holds cols [28j,28j+28) of gate rows
// {u, u+110, u+220, u+330} = 112 weights in TRUE VGPRs; 56 pk_fma/step.
// Quad allreduce = 2 DPP levels. One barrier/step; h,p double-buffered.
// du SOFTWARE-PIPELINED: du_{t-1} (from p published at the last barrier)
// is computed during step t under the pk_fma block; u_t ready at select.
// Gate activation: ONE exp+rcp path per wave (lane j activates gate j via
// tanh(x)=2*sigm(2x)-1), redistributed with 4 quad_perm broadcasts.

#define T784 784
#define H110 110
#define NT   448
#define NCLS 10
#define LOG2E 1.44269504088896340736f

typedef float v2f __attribute__((ext_vector_type(2)));
typedef float v4f __attribute__((ext_vector_type(4)));

__device__ __forceinline__ float frcp(float x)  { return __builtin_amdgcn_rcpf(x); }
__device__ __forceinline__ float fexp2(float x) { return __builtin_amdgcn_exp2f(x); }

__device__ __forceinline__ v2f pk_fma(v2f a, v2f b, v2f c) {
    v2f d;
    asm("v_pk_fma_f32 %0, %1, %2, %3" : "=v"(d) : "v"(a), "v"(b), "v"(c));
    return d;
}

template <int CTRL>
__device__ __forceinline__ float dppmov(float v) {
    return __int_as_float(__builtin_amdgcn_update_dpp(
        __float_as_int(v), __float_as_int(v), CTRL, 0xF, 0xF, false));
}
template <int CTRL>
__device__ __forceinline__ float dppadd(float v) { return v + dppmov<CTRL>(v); }

__global__ __launch_bounds__(NT, 2)
void skiplstm_kernel(const float* __restrict__ x,
                     const float* __restrict__ W_ih,
                     const float* __restrict__ W_hh,
                     const float* __restrict__ b,
                     const float* __restrict__ W_p,
                     const float* __restrict__ b_p,
                     const float* __restrict__ h0,
                     const float* __restrict__ c0,
                     const float* __restrict__ W_fc,
                     const float* __restrict__ b_fc,
                     float* __restrict__ out)
{
    __shared__ __align__(16) float s_hbuf[256];  // double-buffered h (128 each)
    __shared__ float s_pbuf[256];                // double-buffered c*W_p partials
    __shared__ float s_x[T784];

    const int tid  = threadIdx.x;
    const int bb   = blockIdx.x;
    const int unit = tid >> 2;                   // 0..111 (110,111 inactive)
    const int j    = tid & 3;                    // k-slice lane
    const bool act = (unit < H110);

    // ---- weights: w2[g][m] = W_hh[unit+110g, 28j+2m .. +1], m=0..13 ----
    v2f  w2[4][14];
    float bv[4], wv[4];
    #pragma unroll
    for (int g = 0; g < 4; ++g) {
        const int row = unit + H110 * g;
        bv[g] = act ? b[row]    : 0.0f;
        wv[g] = act ? W_ih[row] : 0.0f;
        const float* rp = W_hh + row * H110;
        #pragma unroll
        for (int m = 0; m < 14; ++m) {
            const int k = 28 * j + 2 * m;
            v2f t = {0.f, 0.f};
            if (act) {
                if (k + 0 < H110) t.x = rp[k + 0];
                if (k + 1 < H110) t.y = rp[k + 1];
            }
            w2[g][m] = t;
        }
    }
    float creg = act ? c0[unit] : 0.0f;          // replicated across the quad
    float hreg = act ? h0[unit] : 0.0f;
    const float wp = act ? W_p[unit] : 0.0f;
    const float bp = b_p[0];

    // lane j activates gate j; gate 2 (g) is tanh = 2*sigm(2x)-1
    const bool  isg  = (j == 2);
    const float negk = isg ? (-2.0f * LOG2E) : (-LOG2E);
    const float mulc = isg ? 2.0f : 1.0f;
    const float addc = isg ? -1.0f : 0.0f;

    for (int i = tid; i < 256;  i += NT) { s_hbuf[i] = 0.0f; s_pbuf[i] = 0.0f; }
    for (int i = tid; i < T784; i += NT) s_x[i] = x[bb * T784 + i];
    __syncthreads();
    if (tid < H110) s_hbuf[tid] = h0[tid];
    __syncthreads();

    float u_prev = 1.0f;                         // u_{t-1} carried (per-wave identical)
    int   cnt    = 0;

    auto step = [&](const float* hb, float* hn, const float* pp, float* pn, int t) {
        // ---- issue all DS reads first ----
        const float xt = s_x[t];
        const v4f* h4 = (const v4f*)hb + 7 * j;  // floats [28j, 28j+28)
        const v4f hQ0 = h4[0], hQ1 = h4[1], hQ2 = h4[2], hQ3 = h4[3];
        const v4f hQ4 = h4[4], hQ5 = h4[5], hQ6 = h4[6];
        const int lane = tid & 63;
        const float p0 = pp[lane], p1 = pp[lane + 64];   // for pipelined du

        v2f hv[14];
        hv[0]  = __builtin_shufflevector(hQ0, hQ0, 0, 1);
        hv[1]  = __builtin_shufflevector(hQ0, hQ0, 2, 3);
        hv[2]  = __builtin_shufflevector(hQ1, hQ1, 0, 1);
        hv[3]  = __builtin_shufflevector(hQ1, hQ1, 2, 3);
        hv[4]  = __builtin_shufflevector(hQ2, hQ2, 0, 1);
        hv[5]  = __builtin_shufflevector(hQ2, hQ2, 2, 3);
        hv[6]  = __builtin_shufflevector(hQ3, hQ3, 0, 1);
        hv[7]  = __builtin_shufflevector(hQ3, hQ3, 2, 3);
        hv[8]  = __builtin_shufflevector(hQ4, hQ4, 0, 1);
        hv[9]  = __builtin_shufflevector(hQ4, hQ4, 2, 3);
        hv[10] = __builtin_shufflevector(hQ5, hQ5, 0, 1);
        hv[11] = __builtin_shufflevector(hQ5, hQ5, 2, 3);
        hv[12] = __builtin_shufflevector(hQ6, hQ6, 0, 1);
        hv[13] = __builtin_shufflevector(hQ6, hQ6, 2, 3);

        // ---- 56 pk_fma: 4 gate rows x 28 MACs ----
        v2f acc0 = {0.f, 0.f}, acc1 = {0.f, 0.f};
        v2f acc2 = {0.f, 0.f}, acc3 = {0.f, 0.f};
        #pragma unroll
        for (int m = 0; m < 14; ++m) {
            acc0 = pk_fma(hv[m], w2[0][m], acc0);
            acc1 = pk_fma(hv[m], w2[1][m], acc1);
            acc2 = pk_fma(hv[m], w2[2][m], acc2);
            acc3 = pk_fma(hv[m], w2[3][m], acc3);
        }

        // ---- pipelined du_{t-1} -> u_t (overlaps the fma block's latency) ----
        float v = p0 + p1;
        v = dppadd<0xB1>(v); v = dppadd<0x4E>(v); v = dppadd<0x141>(v);
        v = dppadd<0x140>(v); v = dppadd<0x142>(v); v = dppadd<0x143>(v);
        const float tot = __int_as_float(
            __builtin_amdgcn_readlane(__float_as_int(v), 63));
        const float du = frcp(1.0f + fexp2(-(tot + bp) * LOG2E));   // sigm
        float u_now = (rintf(u_prev) > 0.5f) ? du
                                             : (u_prev + fminf(du, 1.0f - u_prev));
        if (t == 0) u_now = 1.0f;                // no du before step 0
        const bool up = rintf(u_now) > 0.5f;     // ub_t, exactly 0/1
        cnt += up ? 1 : 0;
        u_prev = u_now;

        // ---- fold + quad allreduce (2 DPP levels) ----
        float a0 = (acc0.x + acc0.y) + fmaf(xt, wv[0], bv[0]);
        float a1 = (acc1.x + acc1.y) + fmaf(xt, wv[1], bv[1]);
        float a2 = (acc2.x + acc2.y) + fmaf(xt, wv[2], bv[2]);
        float a3 = (acc3.x + acc3.y) + fmaf(xt, wv[3], bv[3]);
        a0 = dppadd<0xB1>(a0); a1 = dppadd<0xB1>(a1);
        a2 = dppadd<0xB1>(a2); a3 = dppadd<0xB1>(a3);
        a0 = dppadd<0x4E>(a0); a1 = dppadd<0x4E>(a1);
        a2 = dppadd<0x4E>(a2); a3 = dppadd<0x4E>(a3);

        // ---- lane j activates gate j: ONE exp+rcp path per wave ----
        const float t01  = (j & 1) ? a1 : a0;
        const float t23  = (j & 1) ? a3 : a2;
        const float asel = (j & 2) ? t23 : t01;
        const float av   = fmaf(mulc, frcp(1.0f + fexp2(asel * negk)), addc);
        const float gi = dppmov<0x00>(av);
        const float gf = dppmov<0x55>(av);
        const float gg = dppmov<0xAA>(av);
        const float go = dppmov<0xFF>(av);

        const float c_new = fmaf(gf, creg, gi * gg);
        const float th    = fmaf(2.0f, frcp(1.0f + fexp2(c_new * (-2.0f * LOG2E))), -1.0f);
        const float h_new = go * th;
        creg = up ? c_new : creg;
        hreg = up ? h_new : hreg;
        if (act && j == 0) {
            hn[unit] = hreg;
            pn[unit] = creg * wp;                // read by next step's du
        }
        __syncthreads();                         // the ONLY barrier per step
    };

    for (int t = 0; t < T784; t += 2) {
        step(s_hbuf,       s_hbuf + 128, s_pbuf,       s_pbuf + 128, t);
        step(s_hbuf + 128, s_hbuf,       s_pbuf + 128, s_pbuf,       t + 1);
    }

    // epilogue: final h is in buffer 0 (last iter t=783 writes buf 0)
    if (tid < NCLS) {
        float acc = b_fc[tid];
        for (int k = 0; k < H110; ++k)
            acc = fmaf(s_hbuf[k], W_fc[tid * H110 + k], acc);
        out[bb * NCLS + tid] = acc;
    }
    if (tid == 0)
        atomicAdd(out + 256 * NCLS, (float)cnt); // total_u at flat index 2560
}

__global__ void zero_tail_kernel(float* out) {
    if (threadIdx.x == 0) out[256 * NCLS] = 0.0f;   // d_out is poisoned 0xAA
}

extern "C" void kernel_launch(void* const* d_in, const int* in_sizes, int n_in,
                              void* d_out, int out_size, void* d_ws, size_t ws_size,
                              hipStream_t stream) {
    const float* x    = (const float*)d_in[0];
    const float* W_ih = (const float*)d_in[1];
    const float* W_hh = (const float*)d_in[2];
    const float* b    = (const float*)d_in[3];
    const float* W_p  = (const float*)d_in[4];
    const float* b_p  = (const float*)d_in[5];
    const float* h0   = (const float*)d_in[6];
    const float* c0   = (const float*)d_in[7];
    const float* W_fc = (const float*)d_in[8];
    const float* b_fc = (const float*)d_in[9];
    float* out = (float*)d_out;

    zero_tail_kernel<<<1, 64, 0, stream>>>(out);
    skiplstm_kernel<<<256, NT, 0, stream>>>(x, W_ih, W_hh, b, W_p, b_p,
                                            h0, c0, W_fc, b_fc, out);
}

// Round 7
// 582.956 us; speedup vs baseline: 1.8605x; 1.0931x over previous
//
#include <hip/hip_runtime.h>

// SkipLSTM: B=256, T=784, I=1, H=110, NCLS=10
// One block per batch element, 448 threads = 7 waves (2/SIMD -> 256-VGPR cap;
// R6 proved weights stay in arch VGPRs: VGPR_Count=116).
// Quad per unit u; lane j holds cols [28j,28j+28) of gate rows
// {u, u+110, u+220, u+330}, PRE-SCALED by -LOG2E (-2LOG2E for g-row) so the
// activation needs no scaling mul: act = fma(mulc, rcp(1+exp2(a)), addc).
// R7 tightening: asm-fused v_add_f32_dpp / v_mov_b32_dpp (1 instr each,
// update_dpp old-operand lowering was 2), tied-operand pk_fma (no acc copy),
// u>0.5f instead of rintf (identical on [0,1] incl banker's 0.5),
// peeled t=0/1. One barrier/step; h,p double-buffered; du pipelined
// (du_{t-1} computed under step t's fma block from p published last barrier).

#define T784 784
#define H110 110
#define NT   448
#define NCLS 10
#define LOG2E 1.44269504088896340736f

typedef float v2f __attribute__((ext_vector_type(2)));
typedef float v4f __attribute__((ext_vector_type(4)));

__device__ __forceinline__ float frcp(float x)  { return __builtin_amdgcn_rcpf(x); }
__device__ __forceinline__ float fexp2(float x) { return __builtin_amdgcn_exp2f(x); }

__device__ __forceinline__ v2f pk_fma(v2f a, v2f b, v2f c) {
    asm("v_pk_fma_f32 %0, %1, %2, %0" : "+v"(c) : "v"(a), "v"(b));
    return c;
}
// single-instruction DPP adds (src0 gets the DPP swizzle)
__device__ __forceinline__ float add_q1(float v) {  // xor1 within quad
    float d; asm("v_add_f32_dpp %0, %1, %1 quad_perm:[1,0,3,2] row_mask:0xf bank_mask:0xf bound_ctrl:0"
                 : "=v"(d) : "v"(v)); return d;
}
__device__ __forceinline__ float add_q2(float v) {  // xor2 within quad
    float d; asm("v_add_f32_dpp %0, %1, %1 quad_perm:[2,3,0,1] row_mask:0xf bank_mask:0xf bound_ctrl:0"
                 : "=v"(d) : "v"(v)); return d;
}
__device__ __forceinline__ float add_hm(float v) {  // xor4 (row_half_mirror)
    float d; asm("v_add_f32_dpp %0, %1, %1 row_half_mirror row_mask:0xf bank_mask:0xf bound_ctrl:0"
                 : "=v"(d) : "v"(v)); return d;
}
__device__ __forceinline__ float add_rm(float v) {  // xor8 (row_mirror)
    float d; asm("v_add_f32_dpp %0, %1, %1 row_mirror row_mask:0xf bank_mask:0xf bound_ctrl:0"
                 : "=v"(d) : "v"(v)); return d;
}
__device__ __forceinline__ float add_b15(float v) { // row_bcast:15 (invalid lanes keep v)
    float d; asm("v_add_f32_dpp %0, %1, %1 row_bcast:15 row_mask:0xf bank_mask:0xf bound_ctrl:0"
                 : "=v"(d) : "v"(v)); return d;
}
__device__ __forceinline__ float add_b31(float v) { // row_bcast:31
    float d; asm("v_add_f32_dpp %0, %1, %1 row_bcast:31 row_mask:0xf bank_mask:0xf bound_ctrl:0"
                 : "=v"(d) : "v"(v)); return d;
}
template <int L>
__device__ __forceinline__ float qbcast(float v) {  // broadcast quad-lane L
    float d;
    if (L == 0) asm("v_mov_b32_dpp %0, %1 quad_perm:[0,0,0,0] row_mask:0xf bank_mask:0xf bound_ctrl:0" : "=v"(d) : "v"(v));
    if (L == 1) asm("v_mov_b32_dpp %0, %1 quad_perm:[1,1,1,1] row_mask:0xf bank_mask:0xf bound_ctrl:0" : "=v"(d) : "v"(v));
    if (L == 2) asm("v_mov_b32_dpp %0, %1 quad_perm:[2,2,2,2] row_mask:0xf bank_mask:0xf bound_ctrl:0" : "=v"(d) : "v"(v));
    if (L == 3) asm("v_mov_b32_dpp %0, %1 quad_perm:[3,3,3,3] row_mask:0xf bank_mask:0xf bound_ctrl:0" : "=v"(d) : "v"(v));
    return d;
}

__global__ __launch_bounds__(NT, 2)
void skiplstm_kernel(const float* __restrict__ x,
                     const float* __restrict__ W_ih,
                     const float* __restrict__ W_hh,
                     const float* __restrict__ b,
                     const float* __restrict__ W_p,
                     const float* __restrict__ b_p,
                     const float* __restrict__ h0,
                     const float* __restrict__ c0,
                     const float* __restrict__ W_fc,
                     const float* __restrict__ b_fc,
                     float* __restrict__ out)
{
    __shared__ __align__(16) float s_hbuf[256];  // double-buffered h (128 each)
    __shared__ float s_pbuf[256];                // double-buffered c*W_p' partials
    __shared__ float s_x[T784];

    const int tid  = threadIdx.x;
    const int bb   = blockIdx.x;
    const int unit = tid >> 2;                   // 0..111 (110,111 inactive)
    const int j    = tid & 3;                    // k-slice lane
    const bool act = (unit < H110);

    // ---- weights pre-scaled by -LOG2E (g-row: -2LOG2E) ----
    v2f  w2[4][14];
    float bv[4], wv[4];
    #pragma unroll
    for (int g = 0; g < 4; ++g) {
        const float ws = (g == 2) ? (-2.0f * LOG2E) : (-LOG2E);
        const int row = unit + H110 * g;
        bv[g] = act ? b[row]    * ws : 0.0f;
        wv[g] = act ? W_ih[row] * ws : 0.0f;
        const float* rp = W_hh + row * H110;
        #pragma unroll
        for (int m = 0; m < 14; ++m) {
            const int k = 28 * j + 2 * m;
            v2f t = {0.f, 0.f};
            if (act) {
                if (k + 0 < H110) t.x = rp[k + 0] * ws;
                if (k + 1 < H110) t.y = rp[k + 1] * ws;
            }
            w2[g][m] = t;
        }
    }
    float creg = act ? c0[unit] : 0.0f;
    float hreg = act ? h0[unit] : 0.0f;
    const float wpn = act ? (-LOG2E) * W_p[unit] : 0.0f;  // pre-scaled
    const float bpn = (-LOG2E) * b_p[0];

    // lane j activates gate j; gate 2 (g) is tanh = 2*sigm(2x)-1
    const float mulc = (j == 2) ? 2.0f : 1.0f;
    const float addc = (j == 2) ? -1.0f : 0.0f;

    for (int i = tid; i < 256;  i += NT) { s_hbuf[i] = 0.0f; s_pbuf[i] = 0.0f; }
    for (int i = tid; i < T784; i += NT) s_x[i] = x[bb * T784 + i];
    __syncthreads();
    if (tid < H110) s_hbuf[tid] = h0[tid];
    __syncthreads();

    float u_prev = 1.0f;                         // replicated per-wave (identical)
    int   cnt    = 0;

    auto step = [&](const float* hb, float* hn, const float* pp, float* pn,
                    int t, bool first) {
        // ---- issue all LDS reads first ----
        const float xt = s_x[t];
        const v4f* h4 = (const v4f*)hb + 7 * j;  // floats [28j, 28j+28)
        const v4f hQ0 = h4[0], hQ1 = h4[1], hQ2 = h4[2], hQ3 = h4[3];
        const v4f hQ4 = h4[4], hQ5 = h4[5], hQ6 = h4[6];
        const int lane = tid & 63;
        const float p0 = pp[lane], p1 = pp[lane + 64];   // for pipelined du

        v2f hv[14];
        hv[0]  = __builtin_shufflevector(hQ0, hQ0, 0, 1);
        hv[1]  = __builtin_shufflevector(hQ0, hQ0, 2, 3);
        hv[2]  = __builtin_shufflevector(hQ1, hQ1, 0, 1);
        hv[3]  = __builtin_shufflevector(hQ1, hQ1, 2, 3);
        hv[4]  = __builtin_shufflevector(hQ2, hQ2, 0, 1);
        hv[5]  = __builtin_shufflevector(hQ2, hQ2, 2, 3);
        hv[6]  = __builtin_shufflevector(hQ3, hQ3, 0, 1);
        hv[7]  = __builtin_shufflevector(hQ3, hQ3, 2, 3);
        hv[8]  = __builtin_shufflevector(hQ4, hQ4, 0, 1);
        hv[9]  = __builtin_shufflevector(hQ4, hQ4, 2, 3);
        hv[10] = __builtin_shufflevector(hQ5, hQ5, 0, 1);
        hv[11] = __builtin_shufflevector(hQ5, hQ5, 2, 3);
        hv[12] = __builtin_shufflevector(hQ6, hQ6, 0, 1);
        hv[13] = __builtin_shufflevector(hQ6, hQ6, 2, 3);

        // ---- 56 tied pk_fma; bias + x-term folded into acc init ----
        v2f acc0 = {fmaf(xt, wv[0], bv[0]), 0.f};
        v2f acc1 = {fmaf(xt, wv[1], bv[1]), 0.f};
        v2f acc2 = {fmaf(xt, wv[2], bv[2]), 0.f};
        v2f acc3 = {fmaf(xt, wv[3], bv[3]), 0.f};
        #pragma unroll
        for (int m = 0; m < 14; ++m) {
            acc0 = pk_fma(hv[m], w2[0][m], acc0);
            acc1 = pk_fma(hv[m], w2[1][m], acc1);
            acc2 = pk_fma(hv[m], w2[2][m], acc2);
            acc3 = pk_fma(hv[m], w2[3][m], acc3);
        }

        // ---- pipelined du_{t-1} -> u_t (hidden under the fma block) ----
        float u_now;
        if (first) {
            u_now = 1.0f;                        // u0 = 1
        } else {
            float v = p0 + p1;
            v = add_q1(v); v = add_q2(v); v = add_hm(v);
            v = add_rm(v); v = add_b15(v); v = add_b31(v);
            const float tot = __int_as_float(
                __builtin_amdgcn_readlane(__float_as_int(v), 63));
            const float du = frcp(1.0f + fexp2(tot + bpn));      // sigm
            u_now = (u_prev > 0.5f) ? du
                                    : (u_prev + fminf(du, 1.0f - u_prev));
        }
        const bool up = u_now > 0.5f;            // == round-half-even on [0,1]
        cnt += up ? 1 : 0;
        u_prev = u_now;

        // ---- fold + quad allreduce (2 single-instr DPP levels) ----
        float a0 = acc0.x + acc0.y;
        float a1 = acc1.x + acc1.y;
        float a2 = acc2.x + acc2.y;
        float a3 = acc3.x + acc3.y;
        a0 = add_q1(a0); a1 = add_q1(a1); a2 = add_q1(a2); a3 = add_q1(a3);
        a0 = add_q2(a0); a1 = add_q2(a1); a2 = add_q2(a2); a3 = add_q2(a3);

        // ---- lane j activates gate j (pre-scaled: no mul) ----
        const float t01  = (j & 1) ? a1 : a0;
        const float t23  = (j & 1) ? a3 : a2;
        const float asel = (j & 2) ? t23 : t01;
        const float av   = fmaf(mulc, frcp(1.0f + fexp2(asel)), addc);
        const float gi = qbcast<0>(av);
        const float gf = qbcast<1>(av);
        const float gg = qbcast<2>(av);
        const float go = qbcast<3>(av);

        const float c_new = fmaf(gf, creg, gi * gg);
        const float th    = fmaf(2.0f, frcp(1.0f + fexp2(c_new * (-2.0f * LOG2E))), -1.0f);
        const float h_new = go * th;
        creg = up ? c_new : creg;                // ub is exactly 0/1
        hreg = up ? h_new : hreg;
        if (act && j == 0) {
            hn[unit] = hreg;
            pn[unit] = creg * wpn;               // read by next step's du
        }
        __syncthreads();                         // the ONLY barrier per step
    };

    float* const h0b = s_hbuf;
    float* const h1b = s_hbuf + 128;
    float* const p0b = s_pbuf;
    float* const p1b = s_pbuf + 128;

    step(h0b, h1b, p0b, p1b, 0, true);           // peeled: no du before step 0
    step(h1b, h0b, p1b, p0b, 1, false);
    for (int t = 2; t < T784; t += 2) {
        step(h0b, h1b, p0b, p1b, t,     false);
        step(h1b, h0b, p1b, p0b, t + 1, false);
    }

    // epilogue: final h is in buffer 0 (t=783 writes buf 0)
    if (tid < NCLS) {
        float acc = b_fc[tid];
        for (int k = 0; k < H110; ++k)
            acc = fmaf(s_hbuf[k], W_fc[tid * H110 + k], acc);
        out[bb * NCLS + tid] = acc;
    }
    if (tid == 0)
        atomicAdd(out + 256 * NCLS, (float)cnt); // total_u at flat index 2560
}

__global__ void zero_tail_kernel(float* out) {
    if (threadIdx.x == 0) out[256 * NCLS] = 0.0f;   // d_out is poisoned 0xAA
}

extern "C" void kernel_launch(void* const* d_in, const int* in_sizes, int n_in,
                              void* d_out, int out_size, void* d_ws, size_t ws_size,
                              hipStream_t stream) {
    const float* x    = (const float*)d_in[0];
    const float* W_ih = (const float*)d_in[1];
    const float* W_hh = (const float*)d_in[2];
    const float* b    = (const float*)d_in[3];
    const float* W_p  = (const float*)d_in[4];
    const float* b_p  = (const float*)d_in[5];
    const float* h0   = (const float*)d_in[6];
    const float* c0   = (const float*)d_in[7];
    const float* W_fc = (const float*)d_in[8];
    const float* b_fc = (const float*)d_in[9];
    float* out = (float*)d_out;

    zero_tail_kernel<<<1, 64, 0, stream>>>(out);
    skiplstm_kernel<<<256, NT, 0, stream>>>(x, W_ih, W_hh, b, W_p, b_p,
                                            h0, c0, W_fc, b_fc, out);
}

// Round 8
// 529.521 us; speedup vs baseline: 2.0483x; 1.1009x over previous
//
#include <hip/hip_runtime.h>

// SkipLSTM: B=256, T=784, I=1, H=110, NCLS=10
// One block per batch element, 448 threads = 7 waves.
// Quad per unit u; lane j owns cols [28j,28j+28) of gate rows
// {u, u+110, u+220, u+330} as F16 PAIRS -> 56 half2 = 56 VGPRs (R2-R7
// lesson: 112 f32 weight VGPRs always get AGPR-parked, ~100 copy
// instr/step tax; f16+v_dot2_f32_f16 halves storage below the 128 tier).
// MAC: __builtin_amdgcn_fdot2 (2 MACs/instr, f32 scalar acc -> no fold).
// h kept in LDS as f16 (ds_write_b16 / ds_read_b64); c, du, biases, x f32.
// Weights pre-scaled by -LOG2E (-2LOG2E for g-row): act = fma(mulc,
// rcp(1+exp2(a)), addc). One barrier/step; h,p double-buffered; du
// pipelined (du_{t-1} under step t's dot2 block). Single-instr asm DPP.

#define T784 784
#define H110 110
#define NT   448
#define NCLS 10
#define LOG2E 1.44269504088896340736f

typedef _Float16 h2 __attribute__((ext_vector_type(2)));
typedef _Float16 h4 __attribute__((ext_vector_type(4)));

__device__ __forceinline__ float frcp(float x)  { return __builtin_amdgcn_rcpf(x); }
__device__ __forceinline__ float fexp2(float x) { return __builtin_amdgcn_exp2f(x); }

// single-instruction DPP adds (src0 gets the DPP swizzle)
__device__ __forceinline__ float add_q1(float v) {  // xor1 within quad
    float d; asm("v_add_f32_dpp %0, %1, %1 quad_perm:[1,0,3,2] row_mask:0xf bank_mask:0xf bound_ctrl:0"
                 : "=v"(d) : "v"(v)); return d;
}
__device__ __forceinline__ float add_q2(float v) {  // xor2 within quad
    float d; asm("v_add_f32_dpp %0, %1, %1 quad_perm:[2,3,0,1] row_mask:0xf bank_mask:0xf bound_ctrl:0"
                 : "=v"(d) : "v"(v)); return d;
}
__device__ __forceinline__ float add_hm(float v) {  // xor4 (row_half_mirror)
    float d; asm("v_add_f32_dpp %0, %1, %1 row_half_mirror row_mask:0xf bank_mask:0xf bound_ctrl:0"
                 : "=v"(d) : "v"(v)); return d;
}
__device__ __forceinline__ float add_rm(float v) {  // xor8 (row_mirror)
    float d; asm("v_add_f32_dpp %0, %1, %1 row_mirror row_mask:0xf bank_mask:0xf bound_ctrl:0"
                 : "=v"(d) : "v"(v)); return d;
}
__device__ __forceinline__ float add_b15(float v) { // row_bcast:15
    float d; asm("v_add_f32_dpp %0, %1, %1 row_bcast:15 row_mask:0xf bank_mask:0xf bound_ctrl:0"
                 : "=v"(d) : "v"(v)); return d;
}
__device__ __forceinline__ float add_b31(float v) { // row_bcast:31
    float d; asm("v_add_f32_dpp %0, %1, %1 row_bcast:31 row_mask:0xf bank_mask:0xf bound_ctrl:0"
                 : "=v"(d) : "v"(v)); return d;
}
template <int L>
__device__ __forceinline__ float qbcast(float v) {  // broadcast quad-lane L
    float d;
    if (L == 0) asm("v_mov_b32_dpp %0, %1 quad_perm:[0,0,0,0] row_mask:0xf bank_mask:0xf bound_ctrl:0" : "=v"(d) : "v"(v));
    if (L == 1) asm("v_mov_b32_dpp %0, %1 quad_perm:[1,1,1,1] row_mask:0xf bank_mask:0xf bound_ctrl:0" : "=v"(d) : "v"(v));
    if (L == 2) asm("v_mov_b32_dpp %0, %1 quad_perm:[2,2,2,2] row_mask:0xf bank_mask:0xf bound_ctrl:0" : "=v"(d) : "v"(v));
    if (L == 3) asm("v_mov_b32_dpp %0, %1 quad_perm:[3,3,3,3] row_mask:0xf bank_mask:0xf bound_ctrl:0" : "=v"(d) : "v"(v));
    return d;
}

__global__ __launch_bounds__(NT, 2)
void skiplstm_kernel(const float* __restrict__ x,
                     const float* __restrict__ W_ih,
                     const float* __restrict__ W_hh,
                     const float* __restrict__ b,
                     const float* __restrict__ W_p,
                     const float* __restrict__ b_p,
                     const float* __restrict__ h0,
                     const float* __restrict__ c0,
                     const float* __restrict__ W_fc,
                     const float* __restrict__ b_fc,
                     float* __restrict__ out)
{
    __shared__ __align__(16) _Float16 s_h16[256]; // double-buffered h f16 (128 each)
    __shared__ float s_pbuf[256];                 // double-buffered c*W_p' partials
    __shared__ float s_x[T784];

    const int tid  = threadIdx.x;
    const int bb   = blockIdx.x;
    const int unit = tid >> 2;                   // 0..111 (110,111 inactive)
    const int j    = tid & 3;                    // k-slice lane
    const bool act = (unit < H110);

    // ---- f16 weight pairs, pre-scaled by -LOG2E (g-row: -2LOG2E) ----
    h2   w2[4][14];
    float bv[4], wv[4];
    #pragma unroll
    for (int g = 0; g < 4; ++g) {
        const float ws = (g == 2) ? (-2.0f * LOG2E) : (-LOG2E);
        const int row = unit + H110 * g;
        bv[g] = act ? b[row]    * ws : 0.0f;
        wv[g] = act ? W_ih[row] * ws : 0.0f;
        const float* rp = W_hh + row * H110;
        #pragma unroll
        for (int m = 0; m < 14; ++m) {
            const int k = 28 * j + 2 * m;
            float f0 = 0.f, f1 = 0.f;
            if (act) {
                if (k + 0 < H110) f0 = rp[k + 0] * ws;
                if (k + 1 < H110) f1 = rp[k + 1] * ws;
            }
            w2[g][m].x = (_Float16)f0;
            w2[g][m].y = (_Float16)f1;
        }
    }
    float creg = act ? c0[unit] : 0.0f;          // f32 state, replicated in quad
    float hreg = act ? h0[unit] : 0.0f;
    const float wpn = act ? (-LOG2E) * W_p[unit] : 0.0f;  // pre-scaled
    const float bpn = (-LOG2E) * b_p[0];

    // lane j activates gate j; gate 2 (g) is tanh = 2*sigm(2x)-1
    const float mulc = (j == 2) ? 2.0f : 1.0f;
    const float addc = (j == 2) ? -1.0f : 0.0f;

    for (int i = tid; i < 256;  i += NT) { s_h16[i] = (_Float16)0.f; s_pbuf[i] = 0.0f; }
    for (int i = tid; i < T784; i += NT) s_x[i] = x[bb * T784 + i];
    __syncthreads();
    if (tid < H110) s_h16[tid] = (_Float16)h0[tid];  // buf0 init
    __syncthreads();

    float u_prev = 1.0f;                         // replicated per-wave (identical)
    int   cnt    = 0;

    auto step = [&](const _Float16* hb, _Float16* hn,
                    const float* pp, float* pn, int t, bool first) {
        // ---- issue all LDS reads first ----
        const float xt = s_x[t];
        const h4* hp = (const h4*)hb + 7 * j;    // f16 [28j, 28j+28), 8B-aligned
        const h4 hh0 = hp[0], hh1 = hp[1], hh2 = hp[2], hh3 = hp[3];
        const h4 hh4 = hp[4], hh5 = hp[5], hh6 = hp[6];
        const int lane = tid & 63;
        const float p0 = pp[lane], p1 = pp[lane + 64];   // for pipelined du

        h2 hv[14];
        hv[0]  = __builtin_shufflevector(hh0, hh0, 0, 1);
        hv[1]  = __builtin_shufflevector(hh0, hh0, 2, 3);
        hv[2]  = __builtin_shufflevector(hh1, hh1, 0, 1);
        hv[3]  = __builtin_shufflevector(hh1, hh1, 2, 3);
        hv[4]  = __builtin_shufflevector(hh2, hh2, 0, 1);
        hv[5]  = __builtin_shufflevector(hh2, hh2, 2, 3);
        hv[6]  = __builtin_shufflevector(hh3, hh3, 0, 1);
        hv[7]  = __builtin_shufflevector(hh3, hh3, 2, 3);
        hv[8]  = __builtin_shufflevector(hh4, hh4, 0, 1);
        hv[9]  = __builtin_shufflevector(hh4, hh4, 2, 3);
        hv[10] = __builtin_shufflevector(hh5, hh5, 0, 1);
        hv[11] = __builtin_shufflevector(hh5, hh5, 2, 3);
        hv[12] = __builtin_shufflevector(hh6, hh6, 0, 1);
        hv[13] = __builtin_shufflevector(hh6, hh6, 2, 3);

        // ---- 56 v_dot2_f32_f16, scalar f32 accs; bias + x folded into init ----
        float a0 = fmaf(xt, wv[0], bv[0]);
        float a1 = fmaf(xt, wv[1], bv[1]);
        float a2 = fmaf(xt, wv[2], bv[2]);
        float a3 = fmaf(xt, wv[3], bv[3]);
        #pragma unroll
        for (int m = 0; m < 14; ++m) {
            a0 = __builtin_amdgcn_fdot2(hv[m], w2[0][m], a0, false);
            a1 = __builtin_amdgcn_fdot2(hv[m], w2[1][m], a1, false);
            a2 = __builtin_amdgcn_fdot2(hv[m], w2[2][m], a2, false);
            a3 = __builtin_amdgcn_fdot2(hv[m], w2[3][m], a3, false);
        }

        // ---- pipelined du_{t-1} -> u_t (hidden under the dot2 block) ----
        float u_now;
        if (first) {
            u_now = 1.0f;                        // u0 = 1
        } else {
            float v = p0 + p1;
            v = add_q1(v); v = add_q2(v); v = add_hm(v);
            v = add_rm(v); v = add_b15(v); v = add_b31(v);
            const float tot = __int_as_float(
                __builtin_amdgcn_readlane(__float_as_int(v), 63));
            const float du = frcp(1.0f + fexp2(tot + bpn));      // sigm
            u_now = (u_prev > 0.5f) ? du
                                    : (u_prev + fminf(du, 1.0f - u_prev));
        }
        const bool up = u_now > 0.5f;            // == round-half-even on [0,1]
        cnt += up ? 1 : 0;
        u_prev = u_now;

        // ---- quad allreduce (2 single-instr DPP levels) ----
        a0 = add_q1(a0); a1 = add_q1(a1); a2 = add_q1(a2); a3 = add_q1(a3);
        a0 = add_q2(a0); a1 = add_q2(a1); a2 = add_q2(a2); a3 = add_q2(a3);

        // ---- lane j activates gate j (pre-scaled: no mul) ----
        const float t01  = (j & 1) ? a1 : a0;
        const float t23  = (j & 1) ? a3 : a2;
        const float asel = (j & 2) ? t23 : t01;
        const float av   = fmaf(mulc, frcp(1.0f + fexp2(asel)), addc);
        const float gi = qbcast<0>(av);
        const float gf = qbcast<1>(av);
        const float gg = qbcast<2>(av);
        const float go = qbcast<3>(av);

        const float c_new = fmaf(gf, creg, gi * gg);
        const float th    = fmaf(2.0f, frcp(1.0f + fexp2(c_new * (-2.0f * LOG2E))), -1.0f);
        const float h_new = go * th;
        creg = up ? c_new : creg;                // ub is exactly 0/1
        hreg = up ? h_new : hreg;
        if (act && j == 0) {
            hn[unit] = (_Float16)hreg;           // b16 write; 2-way dword alias free
            pn[unit] = creg * wpn;               // read by next step's du (f32)
        }
        __syncthreads();                         // the ONLY barrier per step
    };

    _Float16* const h0b = s_h16;
    _Float16* const h1b = s_h16 + 128;
    float* const p0b = s_pbuf;
    float* const p1b = s_pbuf + 128;

    step(h0b, h1b, p0b, p1b, 0, true);           // peeled: no du before step 0
    step(h1b, h0b, p1b, p0b, 1, false);
    for (int t = 2; t < T784; t += 2) {
        step(h0b, h1b, p0b, p1b, t,     false);
        step(h1b, h0b, p1b, p0b, t + 1, false);
    }

    // epilogue: final h is in buffer 0 (t=783 writes buf 0)
    if (tid < NCLS) {
        float acc = b_fc[tid];
        for (int k = 0; k < H110; ++k)
            acc = fmaf((float)s_h16[k], W_fc[tid * H110 + k], acc);
        out[bb * NCLS + tid] = acc;
    }
    if (tid == 0)
        atomicAdd(out + 256 * NCLS, (float)cnt); // total_u at flat index 2560
}

__global__ void zero_tail_kernel(float* out) {
    if (threadIdx.x == 0) out[256 * NCLS] = 0.0f;   // d_out is poisoned 0xAA
}

extern "C" void kernel_launch(void* const* d_in, const int* in_sizes, int n_in,
                              void* d_out, int out_size, void* d_ws, size_t ws_size,
                              hipStream_t stream) {
    const float* x    = (const float*)d_in[0];
    const float* W_ih = (const float*)d_in[1];
    const float* W_hh = (const float*)d_in[2];
    const float* b    = (const float*)d_in[3];
    const float* W_p  = (const float*)d_in[4];
    const float* b_p  = (const float*)d_in[5];
    const float* h0   = (const float*)d_in[6];
    const float* c0   = (const float*)d_in[7];
    const float* W_fc = (const float*)d_in[8];
    const float* b_fc = (const float*)d_in[9];
    float* out = (float*)d_out;

    zero_tail_kernel<<<1, 64, 0, stream>>>(out);
    skiplstm_kernel<<<256, NT, 0, stream>>>(x, W_ih, W_hh, b, W_p, b_p,
                                            h0, c0, W_fc, b_fc, out);
}